// Round 1
// 252.050 us; speedup vs baseline: 1.0816x; 1.0816x over previous
//
#include <hip/hip_runtime.h>
#include <hip/hip_bf16.h>

// Problem constants (match reference)
#define D_MODEL 2048
#define SEQ_T   2048
#define NQH     16
#define NKVH    4
#define HD      128
#define WIN     256
#define BATCH   2
#define ROWS    (BATCH * SEQ_T)   // 4096
#define L2_10K  13.287712379549449f   // log2(10000)
#define GK      2048              // K of both big GEMMs
#define GNT     64                // GK / 32 K-tiles

typedef __attribute__((ext_vector_type(8))) short bf8_t;   // 8 bf16 in 4 VGPRs
typedef __attribute__((ext_vector_type(4))) float f4_t;    // MFMA acc

__device__ __forceinline__ float bf2f(unsigned short u) {
    union { unsigned int i; float f; } v; v.i = ((unsigned int)u) << 16; return v.f;
}
__device__ __forceinline__ unsigned short f2bf(float f) {
    union { float f; unsigned int i; } v; v.f = f;
    unsigned int x = v.i;
    unsigned int lsb = (x >> 16) & 1u;
    x += 0x7fffu + lsb;           // round-to-nearest-even (finite values only)
    return (unsigned short)(x >> 16);
}

// async global->LDS, 16B per lane; LDS dest = wave-uniform base + lane*16.
__device__ __forceinline__ void async_ld16(const unsigned short* g, unsigned short* l) {
    __builtin_amdgcn_global_load_lds(
        (const __attribute__((address_space(1))) unsigned int*)(g),
        (__attribute__((address_space(3))) unsigned int*)(l), 16, 0, 0);
}

__device__ int sniff_is_f32(const unsigned short* p) {
    int sane = 0;
    for (int i = 0; i < 64; ++i) {
        unsigned short u = p[2 * i];
        int e = (u >> 7) & 0xFF;
        sane += (e >= 100 && e <= 140) ? 1 : 0;
    }
    return sane < 32;
}

// ---------------------------------------------------------------------------
// convert_all: x cast (blocks 0..4095) + all 4 weight transposes (one launch).
// ---------------------------------------------------------------------------
__global__ __launch_bounds__(256)
void convert_all(const float* __restrict__ x,
                 const float* __restrict__ Wq, const float* __restrict__ Wk,
                 const float* __restrict__ Wv, const float* __restrict__ Wo,
                 unsigned short* __restrict__ xb,
                 unsigned short* __restrict__ Wqkvt, unsigned short* __restrict__ Wot) {
    __shared__ unsigned short Ts[32][36];
    int id = blockIdx.x;
    const int t = threadIdx.x;
    if (id < 4096) {
        // streaming cast of x: 2048 elems per block
        int i = (id * 256 + t) * 8;
        float4 a = *(const float4*)(x + i);
        float4 b = *(const float4*)(x + i + 4);
        ushort4 o0, o1;
        o0.x = f2bf(a.x); o0.y = f2bf(a.y); o0.z = f2bf(a.z); o0.w = f2bf(a.w);
        o1.x = f2bf(b.x); o1.y = f2bf(b.y); o1.z = f2bf(b.z); o1.w = f2bf(b.w);
        *(ushort4*)(xb + i)     = o0;
        *(ushort4*)(xb + i + 4) = o1;
        return;
    }
    id -= 4096;
    const float* W; unsigned short* Wt; int N;
    const int K = D_MODEL;
    if (id < 4096)      { W = Wq; Wt = Wqkvt;                          N = 2048; }
    else if (id < 5120) { W = Wk; Wt = Wqkvt + (size_t)2048 * D_MODEL; N = 512;  id -= 4096; }
    else if (id < 6144) { W = Wv; Wt = Wqkvt + (size_t)2560 * D_MODEL; N = 512;  id -= 5120; }
    else                { W = Wo; Wt = Wot;                            N = 2048; id -= 6144; }
    const int ntn = N >> 5;
    const int n0 = (id % ntn) * 32;
    const int k0 = (id / ntn) * 32;
    {
        int r = t >> 3, c = (t & 7) * 4;
        float4 v = *(const float4*)(W + (size_t)(k0 + r) * N + n0 + c);
        Ts[r][c + 0] = f2bf(v.x); Ts[r][c + 1] = f2bf(v.y);
        Ts[r][c + 2] = f2bf(v.z); Ts[r][c + 3] = f2bf(v.w);
    }
    __syncthreads();
    {
        int n = t >> 3, k = (t & 7) * 4;
        ushort4 o;
        o.x = Ts[k + 0][n]; o.y = Ts[k + 1][n];
        o.z = Ts[k + 2][n]; o.w = Ts[k + 3][n];
        *(ushort4*)(Wt + (size_t)(n0 + n) * K + k0 + k) = o;
    }
}

// ---------------------------------------------------------------------------
// gemm256: C = A * Bt^T, 256x256 tile, BK=32, K=2048 fixed.
// 8 waves (2M x 4N), per-wave 128x64 output = acc[8][4] 16x16 frags
// (N-frags strided by 64 so RoPE pairs (d, d+64) are same-wave/same-lane).
// Deep pipeline: ring of 4 LDS K-tile buffers (128 KiB); while computing
// tile t from slot t&3, stage tile t+3 into slot (t+3)&3 = (t-1)&3 -- a
// buffer whose readers all completed before the barrier ending tile t-1
// (race-free by construction). Counted s_waitcnt vmcnt(8) (2 tiles = 8
// global_load_lds per wave stay in flight across barriers; never drains
// to 0 in the main loop). s_setprio(1) around each 32-MFMA cluster.
// LDS swizzle: physical 16B slot = (logical_slot + (row>>1)) & 3, applied
// on BOTH sides (pre-swizzled global source of global_load_lds + swizzled
// ds_read addr) -> each ds_read_b128 spreads 8 consecutive lanes over all
// 8 slot classes = conflict-free.
// mode 1: C fp32 row-major [M][N] (out-proj).
// mode 3: fused QKV epilogue with RoPE (Q/K roped, V chunk-blocked).
// ---------------------------------------------------------------------------
__global__ __launch_bounds__(512, 2)
void gemm256(const unsigned short* __restrict__ A,
             const unsigned short* __restrict__ Bt,
             void* __restrict__ Cq, void* __restrict__ Ck, void* __restrict__ Cvc,
             int N, int mode) {
    __shared__ __align__(16) unsigned short Ls[4][2][8192];   // [slot][A/B][256r x 32k]

    const int tid  = threadIdx.x;
    const int w    = tid >> 6;
    const int lane = tid & 63;
    const int quad = lane >> 4;
    const int lr   = lane & 15;
    const int wm   = w >> 2;          // 0..1  (M wave)
    const int wn   = w & 3;           // 0..3  (N wave)
    const int sl   = ((quad + (lr >> 1)) & 3) * 8;   // swizzled 16B slot (shorts)

    // XCD-aware tile mapping: 16 x ntn grid of 256^2 tiles; each XCD owns a
    // 4(M) x ntn/2(N) contiguous region (per-XCD L2 footprint ~10 MB).
    const int ntn = N >> 8;
    const int g   = blockIdx.x;
    const int xcd = g & 7;
    const int r   = g >> 3;
    const int bm  = (xcd & 3) * 4 + (r & 3);
    const int bn  = (xcd >> 2) * (ntn >> 1) + (r >> 2);
    const int m0  = bm * 256;
    const int n0  = bn * 256;

    // staging source pointers: chunk li = l*512+tid covers LDS 16B chunk li;
    // row = li>>2, physical slot = li&3, logical k-slot = (sp - (row>>1)) & 3.
    const unsigned short* srcA[2];
    const unsigned short* srcB[2];
    int dchunk[2];
    #pragma unroll
    for (int l = 0; l < 2; ++l) {
        int li   = l * 512 + tid;
        int row  = li >> 2;
        int slog = ((li & 3) - ((li >> 3) & 3)) & 3;
        srcA[l]   = A  + (size_t)(m0 + row) * GK + slog * 8;
        srcB[l]   = Bt + (size_t)(n0 + row) * GK + slog * 8;
        dchunk[l] = (l * 512 + w * 64) * 8;   // wave-uniform LDS chunk base (shorts)
    }

    f4_t acc[8][4];
    #pragma unroll
    for (int i = 0; i < 8; ++i)
        #pragma unroll
        for (int j = 0; j < 4; ++j) acc[i][j] = (f4_t){0.f, 0.f, 0.f, 0.f};

#define STAGE(S, KT) do {                                           \
        const int ko_ = (KT) * 32;                                  \
        async_ld16(srcA[0] + ko_, &Ls[S][0][dchunk[0]]);            \
        async_ld16(srcA[1] + ko_, &Ls[S][0][dchunk[1]]);            \
        async_ld16(srcB[0] + ko_, &Ls[S][1][dchunk[0]]);            \
        async_ld16(srcB[1] + ko_, &Ls[S][1][dchunk[1]]);            \
    } while (0)

#define TILE(S) do {                                                          \
        const unsigned short* LA_ = &Ls[S][0][0];                             \
        const unsigned short* LB_ = &Ls[S][1][0];                             \
        bf8_t af[8], bv[4];                                                   \
        _Pragma("unroll")                                                     \
        for (int mf = 0; mf < 8; ++mf)                                        \
            af[mf] = *(const bf8_t*)&LA_[(wm * 128 + mf * 16 + lr) * 32 + sl];\
        _Pragma("unroll")                                                     \
        for (int nf = 0; nf < 4; ++nf)                                        \
            bv[nf] = *(const bf8_t*)&LB_[(wn * 16 + nf * 64 + lr) * 32 + sl]; \
        __builtin_amdgcn_s_setprio(1);                                        \
        _Pragma("unroll")                                                     \
        for (int nf = 0; nf < 4; ++nf)                                        \
            _Pragma("unroll")                                                 \
            for (int mf = 0; mf < 8; ++mf)                                    \
                acc[mf][nf] = __builtin_amdgcn_mfma_f32_16x16x32_bf16(        \
                    af[mf], bv[nf], acc[mf][nf], 0, 0, 0);                    \
        __builtin_amdgcn_s_setprio(0);                                        \
    } while (0)

#define GATE(NN) asm volatile("s_waitcnt vmcnt(" #NN ")" ::: "memory")

    // prologue: stage tiles 0,1,2; wait tile 0 landed (8 = tiles 1,2 in flight)
    STAGE(0, 0); STAGE(1, 1); STAGE(2, 2);
    GATE(8);
    __builtin_amdgcn_s_barrier();

    // steady state: compute t, stage t+3; gate keeps 2 tiles (8 loads) in flight.
    for (int t = 0; t < 61; ++t) {
        STAGE((t + 3) & 3, t + 3);
        TILE(t & 3);
        GATE(8);
        __builtin_amdgcn_s_barrier();
    }
    // epilogue tiles 61..63: drain 8 -> 4 -> 0
    TILE(1); GATE(4); __builtin_amdgcn_s_barrier();
    TILE(2); GATE(0); __builtin_amdgcn_s_barrier();
    TILE(3);

#undef STAGE
#undef TILE
#undef GATE

    // ---- epilogues ----
    // acc[mf][nf][rr]: row = m0 + wm*128 + mf*16 + quad*4 + rr
    //                  col = n0 + wn*16 + nf*64 + lr
    if (mode == 1) {
        float* C = (float*)Cq;
        #pragma unroll
        for (int mf = 0; mf < 8; ++mf)
            #pragma unroll
            for (int nf = 0; nf < 4; ++nf) {
                int c  = n0 + wn * 16 + nf * 64 + lr;
                int rb = m0 + wm * 128 + mf * 16 + quad * 4;
                #pragma unroll
                for (int rr = 0; rr < 4; ++rr)
                    C[(size_t)(rb + rr) * N + c] = acc[mf][nf][rr];
            }
        return;
    }
    if (n0 < 2048 + 512) {
        // Q or K region: RoPE. Pair p (head p of this 256-col block):
        // lo = acc[mf][2p] (cols +p*128 + 0..63), hi = acc[mf][2p+1] (+64).
        const bool isQ = (n0 < 2048);
        unsigned short* Cb = isQ ? (unsigned short*)Cq : (unsigned short*)Ck;
        const int ldc = isQ ? D_MODEL : (NKVH * HD);
        const int cb0 = isQ ? n0 : (n0 - 2048);
        const int dh  = wn * 16 + lr;                       // 0..63
        const float inv = exp2f(-(float)dh * (L2_10K / 64.0f));
        #pragma unroll
        for (int mf = 0; mf < 8; ++mf) {
            #pragma unroll
            for (int rr = 0; rr < 4; ++rr) {
                int row = m0 + wm * 128 + mf * 16 + quad * 4 + rr;
                float tp = (float)(row & (SEQ_T - 1));
                float sn, cs;
                sincosf(tp * inv, &sn, &cs);
                #pragma unroll
                for (int p = 0; p < 2; ++p) {
                    float lo = acc[mf][2 * p][rr], hi = acc[mf][2 * p + 1][rr];
                    size_t base = (size_t)row * ldc + cb0 + wn * 16 + p * 128 + lr;
                    Cb[base]      = f2bf(lo * cs - hi * sn);
                    Cb[base + 64] = f2bf(hi * cs + lo * sn);
                }
            }
        }
    } else {
        // V region: chunk-blocked store Vc[b][kvh][pos>>5][d][pos&31]
        unsigned short* Vc = (unsigned short*)Cvc;
        #pragma unroll
        for (int mf = 0; mf < 8; ++mf)
            #pragma unroll
            for (int nf = 0; nf < 4; ++nf) {
                int n    = (n0 - 2560) + wn * 16 + nf * 64 + lr;   // 0..511
                int kvh2 = n >> 7, d = n & 127;
                int row0 = m0 + wm * 128 + mf * 16 + quad * 4;
                int bb   = row0 >> 11, pos = row0 & (SEQ_T - 1);
                ushort4 o;
                o.x = f2bf(acc[mf][nf][0]); o.y = f2bf(acc[mf][nf][1]);
                o.z = f2bf(acc[mf][nf][2]); o.w = f2bf(acc[mf][nf][3]);
                *(ushort4*)(Vc + (size_t)(bb * 4 + kvh2) * (SEQ_T * HD)
                              + (size_t)(pos >> 5) * 4096 + d * 32 + (pos & 31)) = o;
            }
    }
}

// ---------------------------------------------------------------------------
// Fallback small-tile GEMM (used only if ws_size < 32 MiB).
// ---------------------------------------------------------------------------
__global__ __launch_bounds__(256)
void gemm_dual(const void* __restrict__ A, const void* __restrict__ B,
               void* __restrict__ C, int M, int N, int Kd,
               const unsigned short* __restrict__ sniffp,
               int a_dyn, int c_dyn, int c_trans) {
    __shared__ unsigned short As[64][32];
    __shared__ unsigned short Bs[64][32];
    __shared__ int s_f32;

    const int t = threadIdx.x;
    if (t == 0) s_f32 = sniff_is_f32(sniffp);

    const int m0 = blockIdx.y * 64, n0 = blockIdx.x * 64;
    const int w = t >> 6, lane = t & 63;
    const int wm = w >> 1, wn = w & 1;
    const int quad = lane >> 4, lr = lane & 15;

    f4_t acc[2][2];
    #pragma unroll
    for (int i = 0; i < 2; ++i)
        #pragma unroll
        for (int j = 0; j < 2; ++j)
            acc[i][j] = (f4_t){0.f, 0.f, 0.f, 0.f};

    const int ar = t >> 2, ac = (t & 3) * 8;
    const int bk = t >> 3, bn = (t & 7) * 8;

    __syncthreads();
    const bool in_f32 = (s_f32 != 0);
    const bool a_f32  = in_f32 && (a_dyn != 0);
    const bool c_f32  = in_f32 && (c_dyn != 0);

    for (int k0 = 0; k0 < Kd; k0 += 32) {
        __syncthreads();
        if (a_f32) {
            const float* Af = (const float*)A;
            const float4* pa = (const float4*)(Af + (size_t)(m0 + ar) * Kd + k0 + ac);
            float4 a0 = pa[0], a1 = pa[1];
            unsigned short* d = &As[ar][ac];
            d[0] = f2bf(a0.x); d[1] = f2bf(a0.y); d[2] = f2bf(a0.z); d[3] = f2bf(a0.w);
            d[4] = f2bf(a1.x); d[5] = f2bf(a1.y); d[6] = f2bf(a1.z); d[7] = f2bf(a1.w);
        } else {
            const unsigned short* Au = (const unsigned short*)A;
            *(uint4*)(&As[ar][ac]) = *(const uint4*)(Au + (size_t)(m0 + ar) * Kd + k0 + ac);
        }
        if (in_f32) {
            const float* Bf = (const float*)B;
            const float4* pb = (const float4*)(Bf + (size_t)(k0 + bk) * N + n0 + bn);
            float4 b0 = pb[0], b1 = pb[1];
            Bs[bn + 0][bk] = f2bf(b0.x); Bs[bn + 1][bk] = f2bf(b0.y);
            Bs[bn + 2][bk] = f2bf(b0.z); Bs[bn + 3][bk] = f2bf(b0.w);
            Bs[bn + 4][bk] = f2bf(b1.x); Bs[bn + 5][bk] = f2bf(b1.y);
            Bs[bn + 6][bk] = f2bf(b1.z); Bs[bn + 7][bk] = f2bf(b1.w);
        } else {
            const unsigned short* Bu = (const unsigned short*)B;
            uint4 bv = *(const uint4*)(Bu + (size_t)(k0 + bk) * N + n0 + bn);
            union { uint4 v; unsigned short s[8]; } bu; bu.v = bv;
            #pragma unroll
            for (int j = 0; j < 8; ++j) Bs[bn + j][bk] = bu.s[j];
        }
        __syncthreads();

        bf8_t va0 = *(const bf8_t*)&As[wm * 32 + 0  + lr][quad * 8];
        bf8_t va1 = *(const bf8_t*)&As[wm * 32 + 16 + lr][quad * 8];
        bf8_t vb0 = *(const bf8_t*)&Bs[wn * 32 + 0  + lr][quad * 8];
        bf8_t vb1 = *(const bf8_t*)&Bs[wn * 32 + 16 + lr][quad * 8];

        acc[0][0] = __builtin_amdgcn_mfma_f32_16x16x32_bf16(va0, vb0, acc[0][0], 0, 0, 0);
        acc[0][1] = __builtin_amdgcn_mfma_f32_16x16x32_bf16(va0, vb1, acc[0][1], 0, 0, 0);
        acc[1][0] = __builtin_amdgcn_mfma_f32_16x16x32_bf16(va1, vb0, acc[1][0], 0, 0, 0);
        acc[1][1] = __builtin_amdgcn_mfma_f32_16x16x32_bf16(va1, vb1, acc[1][1], 0, 0, 0);
    }

    if (c_trans) {
        #pragma unroll
        for (int mi = 0; mi < 2; ++mi)
            #pragma unroll
            for (int ni = 0; ni < 2; ++ni) {
                int row0 = m0 + wm * 32 + mi * 16 + quad * 4;
                int col  = n0 + wn * 32 + ni * 16 + lr;   // 0..511
                int kvh2 = col >> 7, d = col & 127;
                int bb   = row0 >> 11, pos = row0 & (SEQ_T - 1);
                ushort4 v;
                v.x = f2bf(acc[mi][ni][0]); v.y = f2bf(acc[mi][ni][1]);
                v.z = f2bf(acc[mi][ni][2]); v.w = f2bf(acc[mi][ni][3]);
                *(ushort4*)((unsigned short*)C + (size_t)(bb * 4 + kvh2) * (SEQ_T * HD)
                              + (size_t)(pos >> 5) * 4096 + d * 32 + (pos & 31)) = v;
            }
    } else {
        #pragma unroll
        for (int mi = 0; mi < 2; ++mi)
            #pragma unroll
            for (int ni = 0; ni < 2; ++ni)
                #pragma unroll
                for (int r = 0; r < 4; ++r) {
                    int row = m0 + wm * 32 + mi * 16 + quad * 4 + r;
                    int col = n0 + wn * 32 + ni * 16 + lr;
                    if (c_f32) ((float*)C)[(size_t)row * N + col] = acc[mi][ni][r];
                    else ((unsigned short*)C)[(size_t)row * N + col] = f2bf(acc[mi][ni][r]);
                }
    }
}

// ---------------------------------------------------------------------------
// RoPE in-place (fallback path only).
// ---------------------------------------------------------------------------
__global__ __launch_bounds__(64)
void rope_kernel(unsigned short* __restrict__ X, int nheads) {
    const int idx = blockIdx.x;
    const int h   = idx % nheads;
    const int row = idx / nheads;
    const int tpos = row % SEQ_T;
    const int i   = threadIdx.x;

    size_t base = (size_t)row * (nheads * HD) + h * HD;
    float inv = exp2f(-(float)i * (L2_10K / 64.0f));
    float a = (float)tpos * inv;
    float s, c;
    sincosf(a, &s, &c);
    float x0 = bf2f(X[base + i]);
    float x1 = bf2f(X[base + i + 64]);
    X[base + i]      = f2bf(x0 * c - x1 * s);
    X[base + i + 64] = f2bf(x1 * c + x0 * s);
}

// ---------------------------------------------------------------------------
// GQA-shared MFMA sliding-window attention, NO-RESCALE softmax (unchanged).
// ---------------------------------------------------------------------------
#define KSS 136   // Ks row stride (272 B: 16B-aligned)
#define PS  72    // P row stride (144 B: 16B-aligned)

__global__ __launch_bounds__(256)
void attn_gqa(unsigned short* __restrict__ Q,
              const unsigned short* __restrict__ K,
              const unsigned short* __restrict__ Vc) {
    __shared__ unsigned short Ks[64][KSS];
    __shared__ unsigned short Vs[8192];          // [slab][d][32]
    __shared__ unsigned short Pw[4][32][PS];     // per-wave P[32 q][64 k]

    const int t    = threadIdx.x;
    const int g    = blockIdx.x;
    const int xcd  = g & 7;
    const int b    = xcd >> 2;
    const int kvh  = xcd & 3;
    const int q0   = (g >> 3) * 32;
    const int w    = t >> 6;
    const int lane = t & 63;
    const int quad = lane >> 4;
    const int lr   = lane & 15;
    const int h    = kvh * 4 + w;
    const float scale = 0.08838834764831845f;    // 1/sqrt(128)

    // Q A-frags (reused all chunks)
    bf8_t qf[2][4];
    #pragma unroll
    for (int mt = 0; mt < 2; ++mt) {
        const unsigned short* qrow =
            Q + (size_t)(b * SEQ_T + q0 + mt * 16 + lr) * D_MODEL + h * HD;
        #pragma unroll
        for (int kk = 0; kk < 4; ++kk)
            qf[mt][kk] = *(const bf8_t*)(qrow + kk * 32 + quad * 8);
    }

    f4_t O[2][8];
    #pragma unroll
    for (int mt = 0; mt < 2; ++mt)
        #pragma unroll
        for (int dt = 0; dt < 8; ++dt) O[mt][dt] = (f4_t){0.f, 0.f, 0.f, 0.f};
    float lpart[2][4];
    #pragma unroll
    for (int mt = 0; mt < 2; ++mt)
        #pragma unroll
        for (int r = 0; r < 4; ++r) lpart[mt][r] = 0.f;

    const size_t vbase = (size_t)(b * 4 + kvh) * (SEQ_T * HD);

    for (int j = 0; j < 5; ++j) {
        const int kb = q0 - 256 + 64 * j;
        if (kb + 63 < 0) continue;               // block-uniform skip
        const bool need_mask = (j == 0) || (j == 4) || (kb < 0);

        __syncthreads();   // previous chunk's LDS reads done
        // --- stage K: all 64 rows, clamped row index (finite; masked later)
        {
            int row = t >> 2, col = (t & 3) * 32;
            int rg = kb + row;
            rg = rg < 0 ? 0 : (rg > SEQ_T - 1 ? SEQ_T - 1 : rg);
            const unsigned short* src =
                K + (size_t)(b * SEQ_T + rg) * (NKVH * HD) + kvh * HD + col;
            #pragma unroll
            for (int i = 0; i < 4; ++i)
                *(uint4*)&Ks[row][col + 8 * i] = *(const uint4*)(src + 8 * i);
        }
        // --- stage V: both 32-key slabs (clamped slab index) ---
        {
            int s0 = kb >> 5;        s0 = s0 < 0 ? 0 : (s0 > 63 ? 63 : s0);
            int s1 = (kb + 32) >> 5; s1 = s1 < 0 ? 0 : (s1 > 63 ? 63 : s1);
            const unsigned short* vb0 = Vc + vbase + (size_t)s0 * 4096;
            const unsigned short* vb1 = Vc + vbase + (size_t)s1 * 4096;
            #pragma unroll
            for (int i = 0; i < 2; ++i) {
                int off = (w * 2 + i) * 512;
                async_ld16(vb0 + off + lane * 8, &Vs[off]);
                async_ld16(vb1 + off + lane * 8, &Vs[4096 + off]);
            }
        }
        __syncthreads();   // staging complete

        // --- QK^T: fully unrolled, 4 key-tiles of 16 ---
        f4_t s[2][4];
        #pragma unroll
        for (int mt = 0; mt < 2; ++mt)
            #pragma unroll
            for (int nt = 0; nt < 4; ++nt) s[mt][nt] = (f4_t){0.f, 0.f, 0.f, 0.f};
        #pragma unroll
        for (int nt = 0; nt < 4; ++nt) {
            #pragma unroll
            for (int kk = 0; kk < 4; ++kk) {
                bf8_t kf = *(const bf8_t*)&Ks[nt * 16 + lr][kk * 32 + quad * 8];
                s[0][nt] = __builtin_amdgcn_mfma_f32_16x16x32_bf16(qf[0][kk], kf, s[0][nt], 0, 0, 0);
                s[1][nt] = __builtin_amdgcn_mfma_f32_16x16x32_bf16(qf[1][kk], kf, s[1][nt], 0, 0, 0);
            }
        }

        // --- no-rescale softmax: p = exp(s*scale) (masked -> 0), P -> LDS ---
        #pragma unroll
        for (int mt = 0; mt < 2; ++mt) {
            #pragma unroll
            for (int r = 0; r < 4; ++r) {
                const int q = q0 + mt * 16 + quad * 4 + r;
                #pragma unroll
                for (int nt = 0; nt < 4; ++nt) {
                    float pj = __expf(s[mt][nt][r] * scale);
                    if (need_mask) {
                        int jg = kb + nt * 16 + lr;
                        bool ok = (jg >= 0) && ((unsigned)(q - jg) < (unsigned)WIN);
                        pj = ok ? pj : 0.f;
                    }
                    lpart[mt][r] += pj;
                    Pw[w][mt * 16 + quad * 4 + r][nt * 16 + lr] = f2bf(pj);
                }
            }
        }

        // --- PV: fully unrolled, both 32-key slabs ---
        bf8_t pf[2][2];
        #pragma unroll
        for (int mt = 0; mt < 2; ++mt)
            #pragma unroll
            for (int kk = 0; kk < 2; ++kk)
                pf[mt][kk] = *(const bf8_t*)&Pw[w][mt * 16 + lr][kk * 32 + quad * 8];
        #pragma unroll
        for (int dt = 0; dt < 8; ++dt)
            #pragma unroll
            for (int kk = 0; kk < 2; ++kk) {
                bf8_t vf = *(const bf8_t*)&Vs[kk * 4096 + (dt * 16 + lr) * 32 + quad * 8];
                O[0][dt] = __builtin_amdgcn_mfma_f32_16x16x32_bf16(pf[0][kk], vf, O[0][dt], 0, 0, 0);
                O[1][dt] = __builtin_amdgcn_mfma_f32_16x16x32_bf16(pf[1][kk], vf, O[1][dt], 0, 0, 0);
            }
    }

    // --- single row-sum reduce over the 16 lr-lanes, then normalize+store ---
    #pragma unroll
    for (int off = 1; off < 16; off <<= 1)
        #pragma unroll
        for (int mt = 0; mt < 2; ++mt)
            #pragma unroll
            for (int r = 0; r < 4; ++r)
                lpart[mt][r] += __shfl_xor(lpart[mt][r], off);

    #pragma unroll
    for (int mt = 0; mt < 2; ++mt) {
        float invl[4];
        #pragma unroll
        for (int r = 0; r < 4; ++r) invl[r] = 1.0f / lpart[mt][r];
        #pragma unroll
        for (int dt = 0; dt < 8; ++dt)
            #pragma unroll
            for (int r = 0; r < 4; ++r)
                Q[(size_t)(b * SEQ_T + q0 + mt * 16 + quad * 4 + r) * D_MODEL
                  + h * HD + dt * 16 + lr] = f2bf(O[mt][dt][r] * invl[r]);
    }
}

// ---------------------------------------------------------------------------
extern "C" void kernel_launch(void* const* d_in, const int* in_sizes, int n_in,
                              void* d_out, int out_size, void* d_ws, size_t ws_size,
                              hipStream_t stream) {
    const float* x  = (const float*)d_in[0];
    const float* Wq = (const float*)d_in[1];
    const float* Wk = (const float*)d_in[2];
    const float* Wv = (const float*)d_in[3];
    const float* Wo = (const float*)d_in[4];
    const unsigned short* sniffp = (const unsigned short*)d_in[1];

    // ws layout (32 MiB): Qb 16MB | Kb 4MB | Vcb 4MB | Wot 8MB
    unsigned short* Qb  = (unsigned short*)d_ws;
    unsigned short* Kb  = Qb + (size_t)ROWS * D_MODEL;
    unsigned short* Vcb = Kb + (size_t)ROWS * (NKVH * HD);
    unsigned short* Wot = Vcb + (size_t)(NKVH * HD) * ROWS;

    dim3 blk(256);

    if (ws_size >= (size_t)32 * 1024 * 1024) {
        // d_out as scratch until final GEMM: xb 16MB | Wqkvt 12.6MB
        unsigned short* xb    = (unsigned short*)d_out;
        unsigned short* Wqkvt = xb + (size_t)ROWS * D_MODEL;   // [3072][2048]

        convert_all<<<dim3(14336), blk, 0, stream>>>(x, Wq, Wk, Wv, Wo, xb, Wqkvt, Wot);

        // fused QKV projection + RoPE epilogue: 16 x 12 tiles of 256^2
        gemm256<<<dim3(192), dim3(512), 0, stream>>>(
            xb, Wqkvt, Qb, Kb, Vcb, D_MODEL + 2 * NKVH * HD, 3);

        // GQA attention (O over Q in place; 512 blocks, (b,kvh) per XCD)
        attn_gqa<<<dim3(512), blk, 0, stream>>>(Qb, Kb, Vcb);

        // out = O @ Wo (fp32 into d_out): 16 x 8 tiles of 256^2
        gemm256<<<dim3(128), dim3(512), 0, stream>>>(
            Qb, Wot, d_out, nullptr, nullptr, D_MODEL, 1);
    } else {
        // Fallback: small-tile path
        gemm_dual<<<dim3(D_MODEL / 64, ROWS / 64), blk, 0, stream>>>(
            x, Wq, Qb, ROWS, D_MODEL, D_MODEL, sniffp, 1, 0, 0);
        gemm_dual<<<dim3((NKVH * HD) / 64, ROWS / 64), blk, 0, stream>>>(
            x, Wk, Kb, ROWS, NKVH * HD, D_MODEL, sniffp, 1, 0, 0);
        gemm_dual<<<dim3((NKVH * HD) / 64, ROWS / 64), blk, 0, stream>>>(
            x, Wv, Vcb, ROWS, NKVH * HD, D_MODEL, sniffp, 1, 0, 1);
        rope_kernel<<<dim3(ROWS * NQH), dim3(64), 0, stream>>>(Qb, NQH);
        rope_kernel<<<dim3(ROWS * NKVH), dim3(64), 0, stream>>>(Kb, NKVH);
        attn_gqa<<<dim3(512), blk, 0, stream>>>(Qb, Kb, Vcb);
        gemm_dual<<<dim3(D_MODEL / 64, ROWS / 64), blk, 0, stream>>>(
            Qb, Wo, d_out, ROWS, D_MODEL, D_MODEL, sniffp, 0, 1, 0);
    }
}

// Round 2
// 240.502 us; speedup vs baseline: 1.1336x; 1.0480x over previous
//
#include <hip/hip_runtime.h>
#include <hip/hip_bf16.h>

// Problem constants (match reference)
#define D_MODEL 2048
#define SEQ_T   2048
#define NQH     16
#define NKVH    4
#define HD      128
#define WIN     256
#define BATCH   2
#define ROWS    (BATCH * SEQ_T)   // 4096
#define L2_10K  13.287712379549449f   // log2(10000)
#define GK      2048              // K of both big GEMMs

typedef __attribute__((ext_vector_type(8))) short bf8_t;   // 8 bf16 in 4 VGPRs
typedef __attribute__((ext_vector_type(4))) float f4_t;    // MFMA acc

__device__ __forceinline__ float bf2f(unsigned short u) {
    union { unsigned int i; float f; } v; v.i = ((unsigned int)u) << 16; return v.f;
}
__device__ __forceinline__ unsigned short f2bf(float f) {
    union { float f; unsigned int i; } v; v.f = f;
    unsigned int x = v.i;
    unsigned int lsb = (x >> 16) & 1u;
    x += 0x7fffu + lsb;           // round-to-nearest-even (finite values only)
    return (unsigned short)(x >> 16);
}

// async global->LDS, 16B per lane; LDS dest = wave-uniform base + lane*16.
__device__ __forceinline__ void async_ld16(const unsigned short* g, unsigned short* l) {
    __builtin_amdgcn_global_load_lds(
        (const __attribute__((address_space(1))) unsigned int*)(g),
        (__attribute__((address_space(3))) unsigned int*)(l), 16, 0, 0);
}

__device__ int sniff_is_f32(const unsigned short* p) {
    int sane = 0;
    for (int i = 0; i < 64; ++i) {
        unsigned short u = p[2 * i];
        int e = (u >> 7) & 0xFF;
        sane += (e >= 100 && e <= 140) ? 1 : 0;
    }
    return sane < 32;
}

// ---------------------------------------------------------------------------
// convert_all: x cast (blocks 0..4095) + all 4 weight transposes (one launch).
// ---------------------------------------------------------------------------
__global__ __launch_bounds__(256)
void convert_all(const float* __restrict__ x,
                 const float* __restrict__ Wq, const float* __restrict__ Wk,
                 const float* __restrict__ Wv, const float* __restrict__ Wo,
                 unsigned short* __restrict__ xb,
                 unsigned short* __restrict__ Wqkvt, unsigned short* __restrict__ Wot) {
    __shared__ unsigned short Ts[32][36];
    int id = blockIdx.x;
    const int t = threadIdx.x;
    if (id < 4096) {
        // streaming cast of x: 2048 elems per block
        int i = (id * 256 + t) * 8;
        float4 a = *(const float4*)(x + i);
        float4 b = *(const float4*)(x + i + 4);
        ushort4 o0, o1;
        o0.x = f2bf(a.x); o0.y = f2bf(a.y); o0.z = f2bf(a.z); o0.w = f2bf(a.w);
        o1.x = f2bf(b.x); o1.y = f2bf(b.y); o1.z = f2bf(b.z); o1.w = f2bf(b.w);
        *(ushort4*)(xb + i)     = o0;
        *(ushort4*)(xb + i + 4) = o1;
        return;
    }
    id -= 4096;
    const float* W; unsigned short* Wt; int N;
    const int K = D_MODEL;
    if (id < 4096)      { W = Wq; Wt = Wqkvt;                          N = 2048; }
    else if (id < 5120) { W = Wk; Wt = Wqkvt + (size_t)2048 * D_MODEL; N = 512;  id -= 4096; }
    else if (id < 6144) { W = Wv; Wt = Wqkvt + (size_t)2560 * D_MODEL; N = 512;  id -= 5120; }
    else                { W = Wo; Wt = Wot;                            N = 2048; id -= 6144; }
    const int ntn = N >> 5;
    const int n0 = (id % ntn) * 32;
    const int k0 = (id / ntn) * 32;
    {
        int r = t >> 3, c = (t & 7) * 4;
        float4 v = *(const float4*)(W + (size_t)(k0 + r) * N + n0 + c);
        Ts[r][c + 0] = f2bf(v.x); Ts[r][c + 1] = f2bf(v.y);
        Ts[r][c + 2] = f2bf(v.z); Ts[r][c + 3] = f2bf(v.w);
    }
    __syncthreads();
    {
        int n = t >> 3, k = (t & 7) * 4;
        ushort4 o;
        o.x = Ts[k + 0][n]; o.y = Ts[k + 1][n];
        o.z = Ts[k + 2][n]; o.w = Ts[k + 3][n];
        *(ushort4*)(Wt + (size_t)(n0 + n) * K + k0 + k) = o;
    }
}

// ---------------------------------------------------------------------------
// gemm256: C = A * Bt^T, 256x256 tile, BK=32, K=2048, fine-phase schedule.
// 8 waves (2M x 4N), per-wave 128x64 output = acc[8][4].
// Ring of 4 LDS K-tile buffers; stage t+3 during tile t (6-phase prefetch).
// Each K-tile split into TWO phases a la m201:
//   ph0: ds_read A[0..3]+B[0..3], STAGE(t+3), bar, setprio(1) 16 MFMA, bar
//   ph1: ds_read A[4..7],                  bar, setprio(1) 16 MFMA, GATE, bar
// GATE(8) counted (= 2 staged tiles in flight), never drains in main loop.
// Swizzle (verified 0 conflicts): phys 16B slot = (quad + (lr>>1)) & 3,
// applied on BOTH sides (pre-swizzled global src + swizzled ds_read addr).
// mode 1: C fp32 row-major [M][N].  mode 3: fused QKV + RoPE epilogue.
// ---------------------------------------------------------------------------
__global__ __launch_bounds__(512, 2)
void gemm256(const unsigned short* __restrict__ A,
             const unsigned short* __restrict__ Bt,
             void* __restrict__ Cq, void* __restrict__ Ck, void* __restrict__ Cvc,
             int N, int mode) {
    __shared__ __align__(16) unsigned short Ls[4][2][8192];   // [slot][A/B][256r x 32k]

    const int tid  = threadIdx.x;
    const int w    = tid >> 6;
    const int lane = tid & 63;
    const int quad = lane >> 4;
    const int lr   = lane & 15;
    const int wm   = w >> 2;          // 0..1  (M wave)
    const int wn   = w & 3;           // 0..3  (N wave)
    const int sl   = ((quad + (lr >> 1)) & 3) * 8;   // swizzled 16B slot (shorts)

    // XCD-aware tile mapping: 16 x ntn grid of 256^2 tiles.
    const int ntn = N >> 8;
    const int g   = blockIdx.x;
    const int xcd = g & 7;
    const int r   = g >> 3;
    const int bm  = (xcd & 3) * 4 + (r & 3);
    const int bn  = (xcd >> 2) * (ntn >> 1) + (r >> 2);
    const int m0  = bm * 256;
    const int n0  = bn * 256;

    // staging source pointers: chunk li = l*512+tid covers LDS 16B chunk li;
    // row = li>>2, physical slot = li&3, logical k-slot = (sp - (row>>1)) & 3.
    const unsigned short* srcA[2];
    const unsigned short* srcB[2];
    int dchunk[2];
    #pragma unroll
    for (int l = 0; l < 2; ++l) {
        int li   = l * 512 + tid;
        int row  = li >> 2;
        int slog = ((li & 3) - ((li >> 3) & 3)) & 3;
        srcA[l]   = A  + (size_t)(m0 + row) * GK + slog * 8;
        srcB[l]   = Bt + (size_t)(n0 + row) * GK + slog * 8;
        dchunk[l] = (l * 512 + w * 64) * 8;   // wave-uniform LDS chunk base (shorts)
    }

    f4_t acc[8][4];
    #pragma unroll
    for (int i = 0; i < 8; ++i)
        #pragma unroll
        for (int j = 0; j < 4; ++j) acc[i][j] = (f4_t){0.f, 0.f, 0.f, 0.f};

#define STAGE(S, KT) do {                                           \
        const int ko_ = (KT) * 32;                                  \
        async_ld16(srcA[0] + ko_, &Ls[S][0][dchunk[0]]);            \
        async_ld16(srcA[1] + ko_, &Ls[S][0][dchunk[1]]);            \
        async_ld16(srcB[0] + ko_, &Ls[S][1][dchunk[0]]);            \
        async_ld16(srcB[1] + ko_, &Ls[S][1][dchunk[1]]);            \
    } while (0)

#define GATE(NN) asm volatile("s_waitcnt vmcnt(" #NN ")" ::: "memory")

    // prologue: stage tiles 0,1,2; wait tile 0 landed (8 = tiles 1,2 in flight)
    STAGE(0, 0); STAGE(1, 1); STAGE(2, 2);
    GATE(8);
    __builtin_amdgcn_s_barrier();

    bf8_t af[4], bv[4];
    for (int t = 0; t < 64; ++t) {
        const int S = t & 3;
        const unsigned short* LA = &Ls[S][0][0];
        const unsigned short* LB = &Ls[S][1][0];

        // --- phase 0: reads for quadrant mf0-3 (+ all B), stage t+3 ---
        #pragma unroll
        for (int mf = 0; mf < 4; ++mf)
            af[mf] = *(const bf8_t*)&LA[(wm * 128 + mf * 16 + lr) * 32 + sl];
        #pragma unroll
        for (int nf = 0; nf < 4; ++nf)
            bv[nf] = *(const bf8_t*)&LB[(wn * 16 + nf * 64 + lr) * 32 + sl];
        if (t < 61) STAGE((t + 3) & 3, t + 3);
        __builtin_amdgcn_s_barrier();
        __builtin_amdgcn_s_setprio(1);
        #pragma unroll
        for (int nf = 0; nf < 4; ++nf)
            #pragma unroll
            for (int mf = 0; mf < 4; ++mf)
                acc[mf][nf] = __builtin_amdgcn_mfma_f32_16x16x32_bf16(
                    af[mf], bv[nf], acc[mf][nf], 0, 0, 0);
        __builtin_amdgcn_s_setprio(0);
        __builtin_amdgcn_s_barrier();

        // --- phase 1: reads for quadrant mf4-7 (B reused from regs) ---
        #pragma unroll
        for (int mf = 0; mf < 4; ++mf)
            af[mf] = *(const bf8_t*)&LA[(wm * 128 + (mf + 4) * 16 + lr) * 32 + sl];
        __builtin_amdgcn_s_barrier();
        __builtin_amdgcn_s_setprio(1);
        #pragma unroll
        for (int nf = 0; nf < 4; ++nf)
            #pragma unroll
            for (int mf = 0; mf < 4; ++mf)
                acc[mf + 4][nf] = __builtin_amdgcn_mfma_f32_16x16x32_bf16(
                    af[mf], bv[nf], acc[mf + 4][nf], 0, 0, 0);
        __builtin_amdgcn_s_setprio(0);
        if (t < 61)      GATE(8);
        else if (t == 61) GATE(4);
        else if (t == 62) GATE(0);
        if (t < 63) __builtin_amdgcn_s_barrier();
    }

#undef STAGE
#undef GATE

    // ---- epilogues ----
    // acc[mf][nf][rr]: row = m0 + wm*128 + mf*16 + quad*4 + rr
    //                  col = n0 + wn*16 + nf*64 + lr
    if (mode == 1) {
        float* C = (float*)Cq;
        #pragma unroll
        for (int mf = 0; mf < 8; ++mf)
            #pragma unroll
            for (int nf = 0; nf < 4; ++nf) {
                int c  = n0 + wn * 16 + nf * 64 + lr;
                int rb = m0 + wm * 128 + mf * 16 + quad * 4;
                #pragma unroll
                for (int rr = 0; rr < 4; ++rr)
                    C[(size_t)(rb + rr) * N + c] = acc[mf][nf][rr];
            }
        return;
    }
    if (n0 < 2048 + 512) {
        // Q or K region: RoPE. Pair p (head p of this 256-col block):
        // lo = acc[mf][2p] (cols +p*128 + 0..63), hi = acc[mf][2p+1] (+64).
        const bool isQ = (n0 < 2048);
        unsigned short* Cb = isQ ? (unsigned short*)Cq : (unsigned short*)Ck;
        const int ldc = isQ ? D_MODEL : (NKVH * HD);
        const int cb0 = isQ ? n0 : (n0 - 2048);
        const int dh  = wn * 16 + lr;                       // 0..63
        const float inv = exp2f(-(float)dh * (L2_10K / 64.0f));
        #pragma unroll
        for (int mf = 0; mf < 8; ++mf) {
            #pragma unroll
            for (int rr = 0; rr < 4; ++rr) {
                int row = m0 + wm * 128 + mf * 16 + quad * 4 + rr;
                float tp = (float)(row & (SEQ_T - 1));
                float sn, cs;
                sincosf(tp * inv, &sn, &cs);
                #pragma unroll
                for (int p = 0; p < 2; ++p) {
                    float lo = acc[mf][2 * p][rr], hi = acc[mf][2 * p + 1][rr];
                    size_t base = (size_t)row * ldc + cb0 + wn * 16 + p * 128 + lr;
                    Cb[base]      = f2bf(lo * cs - hi * sn);
                    Cb[base + 64] = f2bf(hi * cs + lo * sn);
                }
            }
        }
    } else {
        // V region: chunk-blocked store Vc[b][kvh][pos>>5][d][pos&31]
        unsigned short* Vc = (unsigned short*)Cvc;
        #pragma unroll
        for (int mf = 0; mf < 8; ++mf)
            #pragma unroll
            for (int nf = 0; nf < 4; ++nf) {
                int n    = (n0 - 2560) + wn * 16 + nf * 64 + lr;   // 0..511
                int kvh2 = n >> 7, d = n & 127;
                int row0 = m0 + wm * 128 + mf * 16 + quad * 4;
                int bb   = row0 >> 11, pos = row0 & (SEQ_T - 1);
                ushort4 o;
                o.x = f2bf(acc[mf][nf][0]); o.y = f2bf(acc[mf][nf][1]);
                o.z = f2bf(acc[mf][nf][2]); o.w = f2bf(acc[mf][nf][3]);
                *(ushort4*)(Vc + (size_t)(bb * 4 + kvh2) * (SEQ_T * HD)
                              + (size_t)(pos >> 5) * 4096 + d * 32 + (pos & 31)) = o;
            }
    }
}

// ---------------------------------------------------------------------------
// gemm128: C(fp32) = A * Bt^T, 128x256 tile, BK=32, K=2048. Full-fill grid
// (256 blocks for 4096x2048). 8 waves (2M x 4N), per-wave 64x64 = acc[4][4].
// Ring-4 of 24KB tile buffers (96 KiB LDS); one phase per K-tile:
//   {8 ds_read + 3 STAGE(t+3), bar, 16 MFMA (setprio), GATE(6), bar}
// Same verified swizzle scheme as gemm256.
// ---------------------------------------------------------------------------
__global__ __launch_bounds__(512, 2)
void gemm128(const unsigned short* __restrict__ A,
             const unsigned short* __restrict__ Bt,
             float* __restrict__ C, int N) {
    __shared__ __align__(16) unsigned short Ls[4][12288];   // [slot][A 4096 | B 8192]

    const int tid  = threadIdx.x;
    const int w    = tid >> 6;
    const int lane = tid & 63;
    const int quad = lane >> 4;
    const int lr   = lane & 15;
    const int wm   = w >> 2;          // 0..1  (64-row half)
    const int wn   = w & 3;           // 0..3
    const int sl   = ((quad + (lr >> 1)) & 3) * 8;

    // XCD map: 32 x (N/256) grid; per XCD 8(M) x ntn/2(N) region.
    const int ntn = N >> 8;           // 8 for N=2048
    const int g   = blockIdx.x;
    const int xcd = g & 7;
    const int r   = g >> 3;           // 0..31
    const int bm  = (xcd & 3) * 8 + (r & 7);
    const int bn  = (xcd >> 2) * (ntn >> 1) + (r >> 3);
    const int m0  = bm * 128;
    const int n0  = bn * 256;

    // staging: A = 512 chunks (1 round), B = 1024 chunks (2 rounds).
    const int slog = ((tid & 3) - ((tid >> 3) & 3)) & 3;
    const unsigned short* srcA0 = A  + (size_t)(m0 + (tid >> 2)) * GK + slog * 8;
    const unsigned short* srcB0 = Bt + (size_t)(n0 + (tid >> 2)) * GK + slog * 8;
    const unsigned short* srcB1 = Bt + (size_t)(n0 + 128 + (tid >> 2)) * GK + slog * 8;
    const int dch = w * 512;          // wave-uniform chunk base (shorts)

    f4_t acc[4][4];
    #pragma unroll
    for (int i = 0; i < 4; ++i)
        #pragma unroll
        for (int j = 0; j < 4; ++j) acc[i][j] = (f4_t){0.f, 0.f, 0.f, 0.f};

#define STAGEB(S, KT) do {                                          \
        const int ko_ = (KT) * 32;                                  \
        async_ld16(srcA0 + ko_, &Ls[S][dch]);                       \
        async_ld16(srcB0 + ko_, &Ls[S][4096 + dch]);                \
        async_ld16(srcB1 + ko_, &Ls[S][8192 + dch]);                \
    } while (0)

#define GATE(NN) asm volatile("s_waitcnt vmcnt(" #NN ")" ::: "memory")

    STAGEB(0, 0); STAGEB(1, 1); STAGEB(2, 2);
    GATE(6);
    __builtin_amdgcn_s_barrier();

    bf8_t af[4], bv[4];
    for (int t = 0; t < 64; ++t) {
        const int S = t & 3;
        #pragma unroll
        for (int mf = 0; mf < 4; ++mf)
            af[mf] = *(const bf8_t*)&Ls[S][(wm * 64 + mf * 16 + lr) * 32 + sl];
        #pragma unroll
        for (int nf = 0; nf < 4; ++nf)
            bv[nf] = *(const bf8_t*)&Ls[S][4096 + (wn * 16 + nf * 64 + lr) * 32 + sl];
        if (t < 61) STAGEB((t + 3) & 3, t + 3);
        __builtin_amdgcn_s_barrier();
        __builtin_amdgcn_s_setprio(1);
        #pragma unroll
        for (int nf = 0; nf < 4; ++nf)
            #pragma unroll
            for (int mf = 0; mf < 4; ++mf)
                acc[mf][nf] = __builtin_amdgcn_mfma_f32_16x16x32_bf16(
                    af[mf], bv[nf], acc[mf][nf], 0, 0, 0);
        __builtin_amdgcn_s_setprio(0);
        if (t < 61)      GATE(6);
        else if (t == 61) GATE(3);
        else if (t == 62) GATE(0);
        if (t < 63) __builtin_amdgcn_s_barrier();
    }

#undef STAGEB
#undef GATE

    #pragma unroll
    for (int mf = 0; mf < 4; ++mf)
        #pragma unroll
        for (int nf = 0; nf < 4; ++nf) {
            int c  = n0 + wn * 16 + nf * 64 + lr;
            int rb = m0 + wm * 64 + mf * 16 + quad * 4;
            #pragma unroll
            for (int rr = 0; rr < 4; ++rr)
                C[(size_t)(rb + rr) * N + c] = acc[mf][nf][rr];
        }
}

// ---------------------------------------------------------------------------
// Fallback small-tile GEMM (used only if ws_size < 32 MiB).
// ---------------------------------------------------------------------------
__global__ __launch_bounds__(256)
void gemm_dual(const void* __restrict__ A, const void* __restrict__ B,
               void* __restrict__ C, int M, int N, int Kd,
               const unsigned short* __restrict__ sniffp,
               int a_dyn, int c_dyn, int c_trans) {
    __shared__ unsigned short As[64][32];
    __shared__ unsigned short Bs[64][32];
    __shared__ int s_f32;

    const int t = threadIdx.x;
    if (t == 0) s_f32 = sniff_is_f32(sniffp);

    const int m0 = blockIdx.y * 64, n0 = blockIdx.x * 64;
    const int w = t >> 6, lane = t & 63;
    const int wm = w >> 1, wn = w & 1;
    const int quad = lane >> 4, lr = lane & 15;

    f4_t acc[2][2];
    #pragma unroll
    for (int i = 0; i < 2; ++i)
        #pragma unroll
        for (int j = 0; j < 2; ++j)
            acc[i][j] = (f4_t){0.f, 0.f, 0.f, 0.f};

    const int ar = t >> 2, ac = (t & 3) * 8;
    const int bk = t >> 3, bn = (t & 7) * 8;

    __syncthreads();
    const bool in_f32 = (s_f32 != 0);
    const bool a_f32  = in_f32 && (a_dyn != 0);
    const bool c_f32  = in_f32 && (c_dyn != 0);

    for (int k0 = 0; k0 < Kd; k0 += 32) {
        __syncthreads();
        if (a_f32) {
            const float* Af = (const float*)A;
            const float4* pa = (const float4*)(Af + (size_t)(m0 + ar) * Kd + k0 + ac);
            float4 a0 = pa[0], a1 = pa[1];
            unsigned short* d = &As[ar][ac];
            d[0] = f2bf(a0.x); d[1] = f2bf(a0.y); d[2] = f2bf(a0.z); d[3] = f2bf(a0.w);
            d[4] = f2bf(a1.x); d[5] = f2bf(a1.y); d[6] = f2bf(a1.z); d[7] = f2bf(a1.w);
        } else {
            const unsigned short* Au = (const unsigned short*)A;
            *(uint4*)(&As[ar][ac]) = *(const uint4*)(Au + (size_t)(m0 + ar) * Kd + k0 + ac);
        }
        if (in_f32) {
            const float* Bf = (const float*)B;
            const float4* pb = (const float4*)(Bf + (size_t)(k0 + bk) * N + n0 + bn);
            float4 b0 = pb[0], b1 = pb[1];
            Bs[bn + 0][bk] = f2bf(b0.x); Bs[bn + 1][bk] = f2bf(b0.y);
            Bs[bn + 2][bk] = f2bf(b0.z); Bs[bn + 3][bk] = f2bf(b0.w);
            Bs[bn + 4][bk] = f2bf(b1.x); Bs[bn + 5][bk] = f2bf(b1.y);
            Bs[bn + 6][bk] = f2bf(b1.z); Bs[bn + 7][bk] = f2bf(b1.w);
        } else {
            const unsigned short* Bu = (const unsigned short*)B;
            uint4 bv = *(const uint4*)(Bu + (size_t)(k0 + bk) * N + n0 + bn);
            union { uint4 v; unsigned short s[8]; } bu; bu.v = bv;
            #pragma unroll
            for (int j = 0; j < 8; ++j) Bs[bn + j][bk] = bu.s[j];
        }
        __syncthreads();

        bf8_t va0 = *(const bf8_t*)&As[wm * 32 + 0  + lr][quad * 8];
        bf8_t va1 = *(const bf8_t*)&As[wm * 32 + 16 + lr][quad * 8];
        bf8_t vb0 = *(const bf8_t*)&Bs[wn * 32 + 0  + lr][quad * 8];
        bf8_t vb1 = *(const bf8_t*)&Bs[wn * 32 + 16 + lr][quad * 8];

        acc[0][0] = __builtin_amdgcn_mfma_f32_16x16x32_bf16(va0, vb0, acc[0][0], 0, 0, 0);
        acc[0][1] = __builtin_amdgcn_mfma_f32_16x16x32_bf16(va0, vb1, acc[0][1], 0, 0, 0);
        acc[1][0] = __builtin_amdgcn_mfma_f32_16x16x32_bf16(va1, vb0, acc[1][0], 0, 0, 0);
        acc[1][1] = __builtin_amdgcn_mfma_f32_16x16x32_bf16(va1, vb1, acc[1][1], 0, 0, 0);
    }

    if (c_trans) {
        #pragma unroll
        for (int mi = 0; mi < 2; ++mi)
            #pragma unroll
            for (int ni = 0; ni < 2; ++ni) {
                int row0 = m0 + wm * 32 + mi * 16 + quad * 4;
                int col  = n0 + wn * 32 + ni * 16 + lr;   // 0..511
                int kvh2 = col >> 7, d = col & 127;
                int bb   = row0 >> 11, pos = row0 & (SEQ_T - 1);
                ushort4 v;
                v.x = f2bf(acc[mi][ni][0]); v.y = f2bf(acc[mi][ni][1]);
                v.z = f2bf(acc[mi][ni][2]); v.w = f2bf(acc[mi][ni][3]);
                *(ushort4*)((unsigned short*)C + (size_t)(bb * 4 + kvh2) * (SEQ_T * HD)
                              + (size_t)(pos >> 5) * 4096 + d * 32 + (pos & 31)) = v;
            }
    } else {
        #pragma unroll
        for (int mi = 0; mi < 2; ++mi)
            #pragma unroll
            for (int ni = 0; ni < 2; ++ni)
                #pragma unroll
                for (int r = 0; r < 4; ++r) {
                    int row = m0 + wm * 32 + mi * 16 + quad * 4 + r;
                    int col = n0 + wn * 32 + ni * 16 + lr;
                    if (c_f32) ((float*)C)[(size_t)row * N + col] = acc[mi][ni][r];
                    else ((unsigned short*)C)[(size_t)row * N + col] = f2bf(acc[mi][ni][r]);
                }
    }
}

// ---------------------------------------------------------------------------
// RoPE in-place (fallback path only).
// ---------------------------------------------------------------------------
__global__ __launch_bounds__(64)
void rope_kernel(unsigned short* __restrict__ X, int nheads) {
    const int idx = blockIdx.x;
    const int h   = idx % nheads;
    const int row = idx / nheads;
    const int tpos = row % SEQ_T;
    const int i   = threadIdx.x;

    size_t base = (size_t)row * (nheads * HD) + h * HD;
    float inv = exp2f(-(float)i * (L2_10K / 64.0f));
    float a = (float)tpos * inv;
    float s, c;
    sincosf(a, &s, &c);
    float x0 = bf2f(X[base + i]);
    float x1 = bf2f(X[base + i + 64]);
    X[base + i]      = f2bf(x0 * c - x1 * s);
    X[base + i + 64] = f2bf(x1 * c + x0 * s);
}

// ---------------------------------------------------------------------------
// GQA-shared MFMA sliding-window attention, NO-RESCALE softmax (unchanged).
// ---------------------------------------------------------------------------
#define KSS 136   // Ks row stride (272 B: 16B-aligned)
#define PS  72    // P row stride (144 B: 16B-aligned)

__global__ __launch_bounds__(256)
void attn_gqa(unsigned short* __restrict__ Q,
              const unsigned short* __restrict__ K,
              const unsigned short* __restrict__ Vc) {
    __shared__ unsigned short Ks[64][KSS];
    __shared__ unsigned short Vs[8192];          // [slab][d][32]
    __shared__ unsigned short Pw[4][32][PS];     // per-wave P[32 q][64 k]

    const int t    = threadIdx.x;
    const int g    = blockIdx.x;
    const int xcd  = g & 7;
    const int b    = xcd >> 2;
    const int kvh  = xcd & 3;
    const int q0   = (g >> 3) * 32;
    const int w    = t >> 6;
    const int lane = t & 63;
    const int quad = lane >> 4;
    const int lr   = lane & 15;
    const int h    = kvh * 4 + w;
    const float scale = 0.08838834764831845f;    // 1/sqrt(128)

    // Q A-frags (reused all chunks)
    bf8_t qf[2][4];
    #pragma unroll
    for (int mt = 0; mt < 2; ++mt) {
        const unsigned short* qrow =
            Q + (size_t)(b * SEQ_T + q0 + mt * 16 + lr) * D_MODEL + h * HD;
        #pragma unroll
        for (int kk = 0; kk < 4; ++kk)
            qf[mt][kk] = *(const bf8_t*)(qrow + kk * 32 + quad * 8);
    }

    f4_t O[2][8];
    #pragma unroll
    for (int mt = 0; mt < 2; ++mt)
        #pragma unroll
        for (int dt = 0; dt < 8; ++dt) O[mt][dt] = (f4_t){0.f, 0.f, 0.f, 0.f};
    float lpart[2][4];
    #pragma unroll
    for (int mt = 0; mt < 2; ++mt)
        #pragma unroll
        for (int r = 0; r < 4; ++r) lpart[mt][r] = 0.f;

    const size_t vbase = (size_t)(b * 4 + kvh) * (SEQ_T * HD);

    for (int j = 0; j < 5; ++j) {
        const int kb = q0 - 256 + 64 * j;
        if (kb + 63 < 0) continue;               // block-uniform skip
        const bool need_mask = (j == 0) || (j == 4) || (kb < 0);

        __syncthreads();   // previous chunk's LDS reads done
        // --- stage K: all 64 rows, clamped row index (finite; masked later)
        {
            int row = t >> 2, col = (t & 3) * 32;
            int rg = kb + row;
            rg = rg < 0 ? 0 : (rg > SEQ_T - 1 ? SEQ_T - 1 : rg);
            const unsigned short* src =
                K + (size_t)(b * SEQ_T + rg) * (NKVH * HD) + kvh * HD + col;
            #pragma unroll
            for (int i = 0; i < 4; ++i)
                *(uint4*)&Ks[row][col + 8 * i] = *(const uint4*)(src + 8 * i);
        }
        // --- stage V: both 32-key slabs (clamped slab index) ---
        {
            int s0 = kb >> 5;        s0 = s0 < 0 ? 0 : (s0 > 63 ? 63 : s0);
            int s1 = (kb + 32) >> 5; s1 = s1 < 0 ? 0 : (s1 > 63 ? 63 : s1);
            const unsigned short* vb0 = Vc + vbase + (size_t)s0 * 4096;
            const unsigned short* vb1 = Vc + vbase + (size_t)s1 * 4096;
            #pragma unroll
            for (int i = 0; i < 2; ++i) {
                int off = (w * 2 + i) * 512;
                async_ld16(vb0 + off + lane * 8, &Vs[off]);
                async_ld16(vb1 + off + lane * 8, &Vs[4096 + off]);
            }
        }
        __syncthreads();   // staging complete

        // --- QK^T: fully unrolled, 4 key-tiles of 16 ---
        f4_t s[2][4];
        #pragma unroll
        for (int mt = 0; mt < 2; ++mt)
            #pragma unroll
            for (int nt = 0; nt < 4; ++nt) s[mt][nt] = (f4_t){0.f, 0.f, 0.f, 0.f};
        #pragma unroll
        for (int nt = 0; nt < 4; ++nt) {
            #pragma unroll
            for (int kk = 0; kk < 4; ++kk) {
                bf8_t kf = *(const bf8_t*)&Ks[nt * 16 + lr][kk * 32 + quad * 8];
                s[0][nt] = __builtin_amdgcn_mfma_f32_16x16x32_bf16(qf[0][kk], kf, s[0][nt], 0, 0, 0);
                s[1][nt] = __builtin_amdgcn_mfma_f32_16x16x32_bf16(qf[1][kk], kf, s[1][nt], 0, 0, 0);
            }
        }

        // --- no-rescale softmax: p = exp(s*scale) (masked -> 0), P -> LDS ---
        #pragma unroll
        for (int mt = 0; mt < 2; ++mt) {
            #pragma unroll
            for (int r = 0; r < 4; ++r) {
                const int q = q0 + mt * 16 + quad * 4 + r;
                #pragma unroll
                for (int nt = 0; nt < 4; ++nt) {
                    float pj = __expf(s[mt][nt][r] * scale);
                    if (need_mask) {
                        int jg = kb + nt * 16 + lr;
                        bool ok = (jg >= 0) && ((unsigned)(q - jg) < (unsigned)WIN);
                        pj = ok ? pj : 0.f;
                    }
                    lpart[mt][r] += pj;
                    Pw[w][mt * 16 + quad * 4 + r][nt * 16 + lr] = f2bf(pj);
                }
            }
        }

        // --- PV: fully unrolled, both 32-key slabs ---
        bf8_t pf[2][2];
        #pragma unroll
        for (int mt = 0; mt < 2; ++mt)
            #pragma unroll
            for (int kk = 0; kk < 2; ++kk)
                pf[mt][kk] = *(const bf8_t*)&Pw[w][mt * 16 + lr][kk * 32 + quad * 8];
        #pragma unroll
        for (int dt = 0; dt < 8; ++dt)
            #pragma unroll
            for (int kk = 0; kk < 2; ++kk) {
                bf8_t vf = *(const bf8_t*)&Vs[kk * 4096 + (dt * 16 + lr) * 32 + quad * 8];
                O[0][dt] = __builtin_amdgcn_mfma_f32_16x16x32_bf16(pf[0][kk], vf, O[0][dt], 0, 0, 0);
                O[1][dt] = __builtin_amdgcn_mfma_f32_16x16x32_bf16(pf[1][kk], vf, O[1][dt], 0, 0, 0);
            }
    }

    // --- single row-sum reduce over the 16 lr-lanes, then normalize+store ---
    #pragma unroll
    for (int off = 1; off < 16; off <<= 1)
        #pragma unroll
        for (int mt = 0; mt < 2; ++mt)
            #pragma unroll
            for (int r = 0; r < 4; ++r)
                lpart[mt][r] += __shfl_xor(lpart[mt][r], off);

    #pragma unroll
    for (int mt = 0; mt < 2; ++mt) {
        float invl[4];
        #pragma unroll
        for (int r = 0; r < 4; ++r) invl[r] = 1.0f / lpart[mt][r];
        #pragma unroll
        for (int dt = 0; dt < 8; ++dt)
            #pragma unroll
            for (int r = 0; r < 4; ++r)
                Q[(size_t)(b * SEQ_T + q0 + mt * 16 + quad * 4 + r) * D_MODEL
                  + h * HD + dt * 16 + lr] = f2bf(O[mt][dt][r] * invl[r]);
    }
}

// ---------------------------------------------------------------------------
extern "C" void kernel_launch(void* const* d_in, const int* in_sizes, int n_in,
                              void* d_out, int out_size, void* d_ws, size_t ws_size,
                              hipStream_t stream) {
    const float* x  = (const float*)d_in[0];
    const float* Wq = (const float*)d_in[1];
    const float* Wk = (const float*)d_in[2];
    const float* Wv = (const float*)d_in[3];
    const float* Wo = (const float*)d_in[4];
    const unsigned short* sniffp = (const unsigned short*)d_in[1];

    // ws layout (32 MiB): Qb 16MB | Kb 4MB | Vcb 4MB | Wot 8MB
    unsigned short* Qb  = (unsigned short*)d_ws;
    unsigned short* Kb  = Qb + (size_t)ROWS * D_MODEL;
    unsigned short* Vcb = Kb + (size_t)ROWS * (NKVH * HD);
    unsigned short* Wot = Vcb + (size_t)(NKVH * HD) * ROWS;

    dim3 blk(256);

    if (ws_size >= (size_t)32 * 1024 * 1024) {
        // d_out as scratch until final GEMM: xb 16MB | Wqkvt 12.6MB
        unsigned short* xb    = (unsigned short*)d_out;
        unsigned short* Wqkvt = xb + (size_t)ROWS * D_MODEL;   // [3072][2048]

        convert_all<<<dim3(14336), blk, 0, stream>>>(x, Wq, Wk, Wv, Wo, xb, Wqkvt, Wot);

        // fused QKV projection + RoPE epilogue: 16 x 12 tiles of 256^2
        gemm256<<<dim3(192), dim3(512), 0, stream>>>(
            xb, Wqkvt, Qb, Kb, Vcb, D_MODEL + 2 * NKVH * HD, 3);

        // GQA attention (O over Q in place; 512 blocks, (b,kvh) per XCD)
        attn_gqa<<<dim3(512), blk, 0, stream>>>(Qb, Kb, Vcb);

        // out = O @ Wo (fp32 into d_out): 32 x 8 tiles of 128x256, full fill
        gemm128<<<dim3(256), dim3(512), 0, stream>>>(Qb, Wot, (float*)d_out, D_MODEL);
    } else {
        // Fallback: small-tile path
        gemm_dual<<<dim3(D_MODEL / 64, ROWS / 64), blk, 0, stream>>>(
            x, Wq, Qb, ROWS, D_MODEL, D_MODEL, sniffp, 1, 0, 0);
        gemm_dual<<<dim3((NKVH * HD) / 64, ROWS / 64), blk, 0, stream>>>(
            x, Wk, Kb, ROWS, NKVH * HD, D_MODEL, sniffp, 1, 0, 0);
        gemm_dual<<<dim3((NKVH * HD) / 64, ROWS / 64), blk, 0, stream>>>(
            x, Wv, Vcb, ROWS, NKVH * HD, D_MODEL, sniffp, 1, 0, 1);
        rope_kernel<<<dim3(ROWS * NQH), dim3(64), 0, stream>>>(Qb, NQH);
        rope_kernel<<<dim3(ROWS * NKVH), dim3(64), 0, stream>>>(Kb, NKVH);
        attn_gqa<<<dim3(512), blk, 0, stream>>>(Qb, Kb, Vcb);
        gemm_dual<<<dim3(D_MODEL / 64, ROWS / 64), blk, 0, stream>>>(
            Qb, Wo, d_out, ROWS, D_MODEL, D_MODEL, sniffp, 0, 1, 0);
    }
}